// Round 5
// baseline (84.560 us; speedup 1.0000x reference)
//
#include <hip/hip_runtime.h>
#include <math.h>

#define BATCH 8
#define CIN   128
#define COUT  128
#define HH    64
#define WW    64
#define OC    27        // 3*K2
#define KDIM  1152      // CIN*9

typedef unsigned short u16;
typedef unsigned int   u32;
typedef __attribute__((ext_vector_type(8))) short bf16x8;
typedef __attribute__((ext_vector_type(4))) float f32x4;

__device__ __forceinline__ float b2f(u16 u) {
    return __uint_as_float((u32)u << 16);
}
__device__ __forceinline__ u16 f2b(float f) {   // RTNE
    u32 u = __float_as_uint(f);
    return (u16)((u + 0x7fffu + ((u >> 16) & 1u)) >> 16);
}
__device__ __forceinline__ float blo(u32 u) { return __uint_as_float(u << 16); }
__device__ __forceinline__ float bhi(u32 u) { return __uint_as_float(u & 0xffff0000u); }
__device__ __forceinline__ u32 cvtpk(float lo, float hi) {
    u32 r;
    asm("v_cvt_pk_bf16_f32 %0, %1, %2" : "=v"(r) : "v"(lo), "v"(hi));
    return r;
}

// ---------------- K_t: x NCHW f32 -> NHWC bf16 (hi) + residual (lo) ----------------
__global__ __launch_bounds__(256) void k_transpose_x(const float* __restrict__ x,
                                                     u16* __restrict__ xtb,
                                                     u16* __restrict__ xlo) {
    __shared__ float tile[64][65];
    int bid = blockIdx.x;              // 8 b * 2 cblk * 64 hwblk = 1024
    int b   = bid >> 7;
    int c0  = ((bid >> 6) & 1) << 6;
    int hw0 = (bid & 63) << 6;
    int t   = threadIdx.x;
    int ln  = t & 63;
    int cq  = t >> 6;                  // 0..3
#pragma unroll
    for (int r = 0; r < 16; ++r) {
        int c_l = cq * 16 + r;
        tile[c_l][ln] = x[(((size_t)(b * CIN + c0 + c_l)) << 12) + hw0 + ln];
    }
    __syncthreads();
#pragma unroll
    for (int r = 0; r < 16; ++r) {
        int hw_w = cq * 16 + r;
        float v = tile[ln][hw_w];
        u16 hi = f2b(v);
        u16 lo = f2b(v - b2f(hi));
        size_t dst = ((size_t)(b << 12) + hw0 + hw_w) * 128 + c0 + ln;
        xtb[dst] = hi;
        xlo[dst] = lo;
    }
}

// ---------------- K_w: pack main weight into B-fragment order, bf16 ----------------
__global__ __launch_bounds__(256) void k_pack_w(const float* __restrict__ weight,
                                                u16* __restrict__ wbf) {
    int tid = blockIdx.x * 256 + threadIdx.x;    // 576 blocks, exact
    int j  = tid & 7;
    int l  = (tid >> 3) & 63;
    int ni = (tid >> 9) & 7;
    int s  = (tid >> 12) & 3;
    int t9 = tid >> 14;
    int co = ni * 16 + (l & 15);
    int ci = s * 32 + ((l >> 4) << 3) + j;
    wbf[tid] = f2b(weight[co * KDIM + ci * 9 + t9]);
}

// ---------------- K_wo: pack offset-conv weight, hi/lo split, co padded 27->32 ----
__global__ __launch_bounds__(256) void k_pack_woff(const float* __restrict__ w_off,
                                                   u16* __restrict__ wop) {
    int tid = blockIdx.x * 256 + threadIdx.x;    // 288 blocks, exact (73728)
    int j   = tid & 7;
    int l   = (tid >> 3) & 63;
    int ni  = (tid >> 9) & 1;
    int sg  = (tid >> 10) & 3;
    int rest = tid >> 12;
    int t9  = rest % 9;
    int split = rest / 9;
    int co = ni * 16 + (l & 15);
    int ci = sg * 32 + ((l >> 4) << 3) + j;
    float val = (co < OC) ? w_off[co * KDIM + ci * 9 + t9] : 0.f;
    u16 hi = f2b(val);
    u16 lo = f2b(val - b2f(hi));
    wop[tid] = split ? lo : hi;
}

// ---------------- K1: offset conv via MFMA (implicit GEMM, hi/lo split) ----------
// block = 64 px (full row) x 32 co, 4 waves (16 px each). 512 blocks.
// T14: half-1 stage loads issued before half-0 K-loop.
__global__ __launch_bounds__(256) void k_off_mfma(const u16* __restrict__ xtb,
                                                  const u16* __restrict__ xlo,
                                                  const u16* __restrict__ wop,
                                                  const float* __restrict__ b_off,
                                                  float* __restrict__ om) {
    __shared__ __align__(16) u16 Xh[3 * 66 * 64];   // 25344 B
    __shared__ __align__(16) u16 Xl[3 * 66 * 64];

    const int t    = threadIdx.x;
    const int b    = blockIdx.x >> 6;
    const int h    = blockIdx.x & 63;
    const int l    = t & 63;
    const int wv   = t >> 6;            // 0..3 -> px group
    const int row0 = l & 15;
    const int kg   = l >> 4;

    f32x4 acc0 = {0.f, 0.f, 0.f, 0.f};   // co 0..15
    f32x4 acc1 = {0.f, 0.f, 0.f, 0.f};   // co 16..31

    bf16x8 vh_[7], vl_[7];
    const bf16x8 zero8 = {0, 0, 0, 0, 0, 0, 0, 0};

    auto stage_load = [&](int half) {
#pragma unroll
        for (int it = 0; it < 7; ++it) {
            int i = t + it * 256;
            vh_[it] = zero8;
            vl_[it] = zero8;
            if (i < 1584) {
                int row = i / 528;
                int rem = i - row * 528;
                int p = rem >> 3, q = rem & 7;
                int grow = h - 1 + row;
                int gw   = p - 1;
                if ((unsigned)grow < 64u && (unsigned)gw < 64u) {
                    size_t src = ((((size_t)b << 12) + (grow << 6) + gw) << 7) + half * 64 + q * 8;
                    vh_[it] = *(const bf16x8*)(xtb + src);
                    vl_[it] = *(const bf16x8*)(xlo + src);
                }
            }
        }
    };
    auto stage_store = [&]() {
#pragma unroll
        for (int it = 0; it < 7; ++it) {
            int i = t + it * 256;
            if (i < 1584) {
                int row = i / 528;
                int rem = i - row * 528;
                int p = rem >> 3, q = rem & 7;
                int dstb = ((row * 66 + p) << 7) + ((q ^ (p & 7)) << 4);
                *(bf16x8*)((char*)Xh + dstb) = vh_[it];
                *(bf16x8*)((char*)Xl + dstb) = vl_[it];
            }
        }
    };
    auto kloop = [&](int half) {
        for (int tap = 0; tap < 9; ++tap) {
            int kh = tap / 3, kw = tap - kh * 3;
            int p = wv * 16 + row0 + kw;           // 0..65
            int rowb = (kh * 66 + p) << 7;
#pragma unroll
            for (int s = 0; s < 2; ++s) {
                int q = s * 4 + kg;
                int off = rowb + ((q ^ (p & 7)) << 4);
                bf16x8 ah = *(const bf16x8*)((const char*)Xh + off);
                bf16x8 al = *(const bf16x8*)((const char*)Xl + off);
                int sg = half * 2 + s;
                const u16* B = wop + (((tap * 4 + sg)) << 10) + (l << 3);
                bf16x8 bh0 = *(const bf16x8*)(B);
                bf16x8 bh1 = *(const bf16x8*)(B + 512);
                bf16x8 bl0 = *(const bf16x8*)(B + 36864);
                bf16x8 bl1 = *(const bf16x8*)(B + 36864 + 512);
                acc0 = __builtin_amdgcn_mfma_f32_16x16x32_bf16(ah, bh0, acc0, 0, 0, 0);
                acc1 = __builtin_amdgcn_mfma_f32_16x16x32_bf16(ah, bh1, acc1, 0, 0, 0);
                acc0 = __builtin_amdgcn_mfma_f32_16x16x32_bf16(al, bh0, acc0, 0, 0, 0);
                acc1 = __builtin_amdgcn_mfma_f32_16x16x32_bf16(al, bh1, acc1, 0, 0, 0);
                acc0 = __builtin_amdgcn_mfma_f32_16x16x32_bf16(ah, bl0, acc0, 0, 0, 0);
                acc1 = __builtin_amdgcn_mfma_f32_16x16x32_bf16(ah, bl1, acc1, 0, 0, 0);
            }
        }
    };

    stage_load(0);
    stage_store();
    __syncthreads();
    stage_load(1);           // issue early: latency hides under kloop(0)
    kloop(0);
    __syncthreads();         // all waves done reading half-0 X
    stage_store();
    __syncthreads();
    kloop(1);

    // ---- epilogue ----
    int wpx = wv * 16 + (kg << 2);
    int co0 = row0;
    {
        float bb = b_off[co0];
        float4 r = make_float4(acc0.x + bb, acc0.y + bb, acc0.z + bb, acc0.w + bb);
        *(float4*)(om + (((size_t)(b * OC + co0)) << 12) + (h << 6) + wpx) = r;
    }
    int co1 = co0 + 16;
    if (co1 < OC) {
        float bb = b_off[co1];
        float4 r = make_float4(acc1.x + bb, acc1.y + bb, acc1.z + bb, acc1.w + bb);
        if (co1 >= 18) {
            r.x = 1.f / (1.f + expf(-r.x));
            r.y = 1.f / (1.f + expf(-r.y));
            r.z = 1.f / (1.f + expf(-r.z));
            r.w = 1.f / (1.f + expf(-r.w));
        }
        *(float4*)(om + (((size_t)(b * OC + co1)) << 12) + (h << 6) + wpx) = r;
    }
}

// ---------------- K2: bilinear sampling (NHWC bf16) + MFMA GEMM ----------------
// block = 64 px (full row) x 128 cout, 4 waves co-split 32 each. 512 blocks.
// T14: tap t+1 gathers issued into registers before tap t's MFMA cluster.
__global__ __launch_bounds__(256) void k_sample_gemm(const u16* __restrict__ xtb,
                                                     const float* __restrict__ om,
                                                     const u16* __restrict__ wbf,
                                                     const float* __restrict__ bias,
                                                     float* __restrict__ out) {
    __shared__ __align__(16) u16 Abuf[2][64 * 128];   // 32 KB, [buf][px][ch] swizzled
    __shared__ float w4[576][4];
    __shared__ int y0c[576], x0c[576], y1c[576], x1c[576];

    const int t = threadIdx.x;
    const int b = blockIdx.x >> 6;
    const int h = blockIdx.x & 63;

    // ---- phase 0: bilinear params for 64 px x 9 taps ----
    for (int i = t; i < 576; i += 256) {
        int p  = i / 9;
        int tt = i - p * 9;
        const float* ob = om + ((size_t)b * OC) * 4096 + (h << 6) + p;
        float dy = ob[(size_t)tt << 12];
        float dx = ob[(size_t)(9 + tt) << 12];
        float m  = ob[(size_t)(18 + tt) << 12];   // sigmoided in K1
        float py = dy + (float)(h - 1 + tt / 3);
        float px = dx + (float)(p - 1 + tt % 3);
        float y0f = floorf(py), x0f = floorf(px);
        float wy = py - y0f, wx = px - x0f;
        int y0 = (int)y0f, x0 = (int)x0f;
        int y1 = y0 + 1,   x1 = x0 + 1;
        float vy0 = ((unsigned)y0 < 64u) ? 1.f : 0.f;
        float vy1 = ((unsigned)y1 < 64u) ? 1.f : 0.f;
        float vx0 = ((unsigned)x0 < 64u) ? 1.f : 0.f;
        float vx1 = ((unsigned)x1 < 64u) ? 1.f : 0.f;
        w4[i][0] = (1.f - wy) * (1.f - wx) * m * vy0 * vx0;
        w4[i][1] = (1.f - wy) * wx         * m * vy0 * vx1;
        w4[i][2] = wy         * (1.f - wx) * m * vy1 * vx0;
        w4[i][3] = wy         * wx         * m * vy1 * vx1;
        y0c[i] = min(max(y0, 0), 63);
        y1c[i] = min(max(y1, 0), 63);
        x0c[i] = min(max(x0, 0), 63);
        x1c[i] = min(max(x1, 0), 63);
    }
    __syncthreads();

    f32x4 acc[4][2];
#pragma unroll
    for (int pt = 0; pt < 4; ++pt)
#pragma unroll
        for (int nt = 0; nt < 2; ++nt) acc[pt][nt] = (f32x4){0.f, 0.f, 0.f, 0.f};

    const int l    = t & 63;
    const int wv   = t >> 6;
    const int row0 = l & 15;
    const int kg   = l >> 4;

    const int sp = t >> 2;          // sampling: pixel 0..63
    const int sc = t & 3;           // sampling: 16B sub-chunk
    const u16* xb = xtb + ((size_t)b << 19);

    uint4 g_[4][4];                 // [k-chunk][corner] gather staging (64 VGPR)

    auto sample_load = [&](int tt) {
        int pi = sp * 9 + tt;
        int o00 = ((y0c[pi] << 6) | x0c[pi]) << 7;
        int o01 = ((y0c[pi] << 6) | x1c[pi]) << 7;
        int o10 = ((y1c[pi] << 6) | x0c[pi]) << 7;
        int o11 = ((y1c[pi] << 6) | x1c[pi]) << 7;
#pragma unroll
        for (int k = 0; k < 4; ++k) {
            int ch = k * 32 + sc * 8;            // 4-lane groups load 64B contiguous
            g_[k][0] = *(const uint4*)(xb + o00 + ch);
            g_[k][1] = *(const uint4*)(xb + o01 + ch);
            g_[k][2] = *(const uint4*)(xb + o10 + ch);
            g_[k][3] = *(const uint4*)(xb + o11 + ch);
        }
    };

    auto sample_finish = [&](int tt, int buf) {
        int pi = sp * 9 + tt;
        float4 W = *(const float4*)(&w4[pi][0]);
        u16* dst = &Abuf[buf][0];
#pragma unroll
        for (int k = 0; k < 4; ++k) {
            uint4 a00 = g_[k][0], a01 = g_[k][1], a10 = g_[k][2], a11 = g_[k][3];
            uint4 ow;
            {
                float e0 = W.x * blo(a00.x) + W.y * blo(a01.x) + W.z * blo(a10.x) + W.w * blo(a11.x);
                float e1 = W.x * bhi(a00.x) + W.y * bhi(a01.x) + W.z * bhi(a10.x) + W.w * bhi(a11.x);
                ow.x = cvtpk(e0, e1);
            }
            {
                float e0 = W.x * blo(a00.y) + W.y * blo(a01.y) + W.z * blo(a10.y) + W.w * blo(a11.y);
                float e1 = W.x * bhi(a00.y) + W.y * bhi(a01.y) + W.z * bhi(a10.y) + W.w * bhi(a11.y);
                ow.y = cvtpk(e0, e1);
            }
            {
                float e0 = W.x * blo(a00.z) + W.y * blo(a01.z) + W.z * blo(a10.z) + W.w * blo(a11.z);
                float e1 = W.x * bhi(a00.z) + W.y * bhi(a01.z) + W.z * bhi(a10.z) + W.w * bhi(a11.z);
                ow.z = cvtpk(e0, e1);
            }
            {
                float e0 = W.x * blo(a00.w) + W.y * blo(a01.w) + W.z * blo(a10.w) + W.w * blo(a11.w);
                float e1 = W.x * bhi(a00.w) + W.y * bhi(a01.w) + W.z * bhi(a10.w) + W.w * bhi(a11.w);
                ow.w = cvtpk(e0, e1);
            }
            int q16 = k * 4 + sc;
            *(uint4*)((char*)dst + (sp << 8) + ((q16 ^ (sp & 7)) << 4)) = ow;
        }
    };

    auto domfma = [&](int t9, int buf) {
        const char* Ab = (const char*)&Abuf[buf][0];
#pragma unroll
        for (int s = 0; s < 4; ++s) {
            int q = s * 4 + kg;
            int sw = (q ^ (row0 & 7)) << 4;
            bf16x8 a[4];
#pragma unroll
            for (int pt = 0; pt < 4; ++pt)
                a[pt] = *(const bf16x8*)(Ab + ((pt * 16 + row0) << 8) + sw);
            const u16* B = wbf + ((size_t)t9 << 14) + (s << 12) + (wv << 10) + (l << 3);
            bf16x8 b0 = *(const bf16x8*)(B);
            bf16x8 b1 = *(const bf16x8*)(B + 512);
#pragma unroll
            for (int pt = 0; pt < 4; ++pt) {
                acc[pt][0] = __builtin_amdgcn_mfma_f32_16x16x32_bf16(a[pt], b0, acc[pt][0], 0, 0, 0);
                acc[pt][1] = __builtin_amdgcn_mfma_f32_16x16x32_bf16(a[pt], b1, acc[pt][1], 0, 0, 0);
            }
        }
    };

    sample_load(0);
    sample_finish(0, 0);
    __syncthreads();
    for (int tt = 0; tt < 9; ++tt) {
        if (tt < 8) sample_load(tt + 1);        // issue gathers early
        domfma(tt, tt & 1);                     // MFMA covers gather latency
        if (tt < 8) sample_finish(tt + 1, (tt + 1) & 1);
        __syncthreads();
    }

    // ---- epilogue: acc -> LDS (swizzled f32 [co][px]) -> coalesced global ----
    {
        float* outs = (float*)&Abuf[0][0];    // 128co x 64px f32 = 32 KB
#pragma unroll
        for (int pt = 0; pt < 4; ++pt)
#pragma unroll
            for (int nt = 0; nt < 2; ++nt) {
                int co  = wv * 32 + nt * 16 + row0;
                int pxq = pt * 4 + kg;
                *(f32x4*)((char*)outs + (co << 8) + ((pxq ^ (co & 7)) << 4)) = acc[pt][nt];
            }
    }
    __syncthreads();
    {
        const float* outs = (const float*)&Abuf[0][0];
        int co = t >> 1, ph = t & 1;
        float bb = bias[co];
        float* og = out + (((size_t)(b * COUT + co)) << 12) + (h << 6) + ph * 32;
#pragma unroll
        for (int j = 0; j < 8; ++j) {
            int pxq = ph * 8 + j;
            f32x4 v = *(const f32x4*)((const char*)outs + (co << 8) + ((pxq ^ (co & 7)) << 4));
            float4 r = make_float4(v.x + bb, v.y + bb, v.z + bb, v.w + bb);
            *reinterpret_cast<float4*>(og + j * 4) = r;
        }
    }
}

// ---------------- host ----------------
extern "C" void kernel_launch(void* const* d_in, const int* in_sizes, int n_in,
                              void* d_out, int out_size, void* d_ws, size_t ws_size,
                              hipStream_t stream) {
    const float* x      = (const float*)d_in[0];
    const float* w_off  = (const float*)d_in[1];
    const float* b_off  = (const float*)d_in[2];
    const float* weight = (const float*)d_in[3];
    const float* bias   = (const float*)d_in[4];
    float* out = (float*)d_out;

    float* om  = (float*)d_ws;                        // 884736 f32
    u16*   xtb = (u16*)(om + 884736);                 // 4194304 u16 (NHWC bf16 hi)
    u16*   wbf = xtb + 4194304;                       // 147456 u16 (main B-frags)
    u16*   wop = wbf + 147456;                        // 73728 u16 (offset B-frags hi/lo)
    u16*   xlo = (u16*)d_out;                         // 8 MB scratch inside out (16.7 MB);
                                                      // consumed before k_sample_gemm writes out

    k_pack_w<<<576, 256, 0, stream>>>(weight, wbf);
    k_pack_woff<<<288, 256, 0, stream>>>(w_off, wop);
    k_transpose_x<<<1024, 256, 0, stream>>>(x, xtb, xlo);
    k_off_mfma<<<512, 256, 0, stream>>>(xtb, xlo, wop, b_off, om);
    k_sample_gemm<<<512, 256, 0, stream>>>(xtb, om, wbf, bias, out);
}

// Round 6
// 76.063 us; speedup vs baseline: 1.1117x; 1.1117x over previous
//
#include <hip/hip_runtime.h>
#include <math.h>

#define BATCH 8
#define CIN   128
#define COUT  128
#define HH    64
#define WW    64
#define OC    27        // 3*K2
#define KDIM  1152      // CIN*9

typedef unsigned short u16;
typedef unsigned int   u32;
typedef __attribute__((ext_vector_type(8))) short bf16x8;
typedef __attribute__((ext_vector_type(4))) float f32x4;

__device__ __forceinline__ float b2f(u16 u) {
    return __uint_as_float((u32)u << 16);
}
__device__ __forceinline__ u16 f2b(float f) {   // RTNE
    u32 u = __float_as_uint(f);
    return (u16)((u + 0x7fffu + ((u >> 16) & 1u)) >> 16);
}
__device__ __forceinline__ float blo(u32 u) { return __uint_as_float(u << 16); }
__device__ __forceinline__ float bhi(u32 u) { return __uint_as_float(u & 0xffff0000u); }
__device__ __forceinline__ u32 cvtpk(float lo, float hi) {
    u32 r;
    asm("v_cvt_pk_bf16_f32 %0, %1, %2" : "=v"(r) : "v"(lo), "v"(hi));
    return r;
}

// XCD-ownership swizzle: grid must be 8*K; XCD (o%8) gets logical blocks [ (o%8)*K, ... )
// so each XCD owns exactly one image end-to-end (dispatch round-robins o%8 -> XCD).
__device__ __forceinline__ int xswiz(int o, int K) { return (o & 7) * K + (o >> 3); }

// ---------------- K_t: x NCHW f32 -> NHWC bf16 (hi) + residual (lo) ----------------
__global__ __launch_bounds__(256) void k_transpose_x(const float* __restrict__ x,
                                                     u16* __restrict__ xtb,
                                                     u16* __restrict__ xlo) {
    __shared__ float tile[64][65];
    int bid = xswiz(blockIdx.x, 128);  // 8 b * (2 cblk * 64 hwblk = 128)
    int b   = bid >> 7;
    int c0  = ((bid >> 6) & 1) << 6;
    int hw0 = (bid & 63) << 6;
    int t   = threadIdx.x;
    int ln  = t & 63;
    int cq  = t >> 6;                  // 0..3
#pragma unroll
    for (int r = 0; r < 16; ++r) {
        int c_l = cq * 16 + r;
        tile[c_l][ln] = x[(((size_t)(b * CIN + c0 + c_l)) << 12) + hw0 + ln];
    }
    __syncthreads();
#pragma unroll
    for (int r = 0; r < 16; ++r) {
        int hw_w = cq * 16 + r;
        float v = tile[ln][hw_w];
        u16 hi = f2b(v);
        u16 lo = f2b(v - b2f(hi));
        size_t dst = ((size_t)(b << 12) + hw0 + hw_w) * 128 + c0 + ln;
        xtb[dst] = hi;
        xlo[dst] = lo;
    }
}

// ---------------- K_w: pack main weight into B-fragment order, bf16 ----------------
__global__ __launch_bounds__(256) void k_pack_w(const float* __restrict__ weight,
                                                u16* __restrict__ wbf) {
    int tid = blockIdx.x * 256 + threadIdx.x;    // 576 blocks, exact
    int j  = tid & 7;
    int l  = (tid >> 3) & 63;
    int ni = (tid >> 9) & 7;
    int s  = (tid >> 12) & 3;
    int t9 = tid >> 14;
    int co = ni * 16 + (l & 15);
    int ci = s * 32 + ((l >> 4) << 3) + j;
    wbf[tid] = f2b(weight[co * KDIM + ci * 9 + t9]);
}

// ---------------- K_wo: pack offset-conv weight, hi/lo split, co padded 27->32 ----
__global__ __launch_bounds__(256) void k_pack_woff(const float* __restrict__ w_off,
                                                   u16* __restrict__ wop) {
    int tid = blockIdx.x * 256 + threadIdx.x;    // 288 blocks, exact (73728)
    int j   = tid & 7;
    int l   = (tid >> 3) & 63;
    int ni  = (tid >> 9) & 1;
    int sg  = (tid >> 10) & 3;
    int rest = tid >> 12;
    int t9  = rest % 9;
    int split = rest / 9;
    int co = ni * 16 + (l & 15);
    int ci = sg * 32 + ((l >> 4) << 3) + j;
    float val = (co < OC) ? w_off[co * KDIM + ci * 9 + t9] : 0.f;
    u16 hi = f2b(val);
    u16 lo = f2b(val - b2f(hi));
    wop[tid] = split ? lo : hi;
}

// ---------------- K1: offset conv via MFMA (implicit GEMM, hi/lo split) ----------
// block = 64 px (full row) x 32 co, 4 waves (16 px each). 512 blocks.
__global__ __launch_bounds__(256) void k_off_mfma(const u16* __restrict__ xtb,
                                                  const u16* __restrict__ xlo,
                                                  const u16* __restrict__ wop,
                                                  const float* __restrict__ b_off,
                                                  float* __restrict__ om) {
    __shared__ __align__(16) u16 Xh[3 * 66 * 64];   // 25344 B
    __shared__ __align__(16) u16 Xl[3 * 66 * 64];

    const int t    = threadIdx.x;
    const int lb   = xswiz(blockIdx.x, 64);
    const int b    = lb >> 6;
    const int h    = lb & 63;
    const int l    = t & 63;
    const int wv   = t >> 6;            // 0..3 -> px group
    const int row0 = l & 15;
    const int kg   = l >> 4;

    f32x4 acc0 = {0.f, 0.f, 0.f, 0.f};   // co 0..15
    f32x4 acc1 = {0.f, 0.f, 0.f, 0.f};   // co 16..31

    bf16x8 vh_[7], vl_[7];
    const bf16x8 zero8 = {0, 0, 0, 0, 0, 0, 0, 0};

    auto stage_load = [&](int half) {
#pragma unroll
        for (int it = 0; it < 7; ++it) {
            int i = t + it * 256;
            vh_[it] = zero8;
            vl_[it] = zero8;
            if (i < 1584) {
                int row = i / 528;
                int rem = i - row * 528;
                int p = rem >> 3, q = rem & 7;
                int grow = h - 1 + row;
                int gw   = p - 1;
                if ((unsigned)grow < 64u && (unsigned)gw < 64u) {
                    size_t src = ((((size_t)b << 12) + (grow << 6) + gw) << 7) + half * 64 + q * 8;
                    vh_[it] = *(const bf16x8*)(xtb + src);
                    vl_[it] = *(const bf16x8*)(xlo + src);
                }
            }
        }
    };
    auto stage_store = [&]() {
#pragma unroll
        for (int it = 0; it < 7; ++it) {
            int i = t + it * 256;
            if (i < 1584) {
                int row = i / 528;
                int rem = i - row * 528;
                int p = rem >> 3, q = rem & 7;
                int dstb = ((row * 66 + p) << 7) + ((q ^ (p & 7)) << 4);
                *(bf16x8*)((char*)Xh + dstb) = vh_[it];
                *(bf16x8*)((char*)Xl + dstb) = vl_[it];
            }
        }
    };
    auto kloop = [&](int half) {
        for (int tap = 0; tap < 9; ++tap) {
            int kh = tap / 3, kw = tap - kh * 3;
            int p = wv * 16 + row0 + kw;           // 0..65
            int rowb = (kh * 66 + p) << 7;
#pragma unroll
            for (int s = 0; s < 2; ++s) {
                int q = s * 4 + kg;
                int off = rowb + ((q ^ (p & 7)) << 4);
                bf16x8 ah = *(const bf16x8*)((const char*)Xh + off);
                bf16x8 al = *(const bf16x8*)((const char*)Xl + off);
                int sg = half * 2 + s;
                const u16* B = wop + (((tap * 4 + sg)) << 10) + (l << 3);
                bf16x8 bh0 = *(const bf16x8*)(B);
                bf16x8 bh1 = *(const bf16x8*)(B + 512);
                bf16x8 bl0 = *(const bf16x8*)(B + 36864);
                bf16x8 bl1 = *(const bf16x8*)(B + 36864 + 512);
                acc0 = __builtin_amdgcn_mfma_f32_16x16x32_bf16(ah, bh0, acc0, 0, 0, 0);
                acc1 = __builtin_amdgcn_mfma_f32_16x16x32_bf16(ah, bh1, acc1, 0, 0, 0);
                acc0 = __builtin_amdgcn_mfma_f32_16x16x32_bf16(al, bh0, acc0, 0, 0, 0);
                acc1 = __builtin_amdgcn_mfma_f32_16x16x32_bf16(al, bh1, acc1, 0, 0, 0);
                acc0 = __builtin_amdgcn_mfma_f32_16x16x32_bf16(ah, bl0, acc0, 0, 0, 0);
                acc1 = __builtin_amdgcn_mfma_f32_16x16x32_bf16(ah, bl1, acc1, 0, 0, 0);
            }
        }
    };

    stage_load(0);
    stage_store();
    __syncthreads();
    stage_load(1);           // issue early: latency hides under kloop(0)
    kloop(0);
    __syncthreads();         // all waves done reading half-0 X
    stage_store();
    __syncthreads();
    kloop(1);

    // ---- epilogue ----
    int wpx = wv * 16 + (kg << 2);
    int co0 = row0;
    {
        float bb = b_off[co0];
        float4 r = make_float4(acc0.x + bb, acc0.y + bb, acc0.z + bb, acc0.w + bb);
        *(float4*)(om + (((size_t)(b * OC + co0)) << 12) + (h << 6) + wpx) = r;
    }
    int co1 = co0 + 16;
    if (co1 < OC) {
        float bb = b_off[co1];
        float4 r = make_float4(acc1.x + bb, acc1.y + bb, acc1.z + bb, acc1.w + bb);
        if (co1 >= 18) {
            r.x = 1.f / (1.f + expf(-r.x));
            r.y = 1.f / (1.f + expf(-r.y));
            r.z = 1.f / (1.f + expf(-r.z));
            r.w = 1.f / (1.f + expf(-r.w));
        }
        *(float4*)(om + (((size_t)(b * OC + co1)) << 12) + (h << 6) + wpx) = r;
    }
}

// ---------------- K2: bilinear sampling (NHWC bf16) + MFMA GEMM ----------------
// block = 64 px (full row) x 128 cout, 4 waves co-split 32 each. 512 blocks.
__global__ __launch_bounds__(256) void k_sample_gemm(const u16* __restrict__ xtb,
                                                     const float* __restrict__ om,
                                                     const u16* __restrict__ wbf,
                                                     const float* __restrict__ bias,
                                                     float* __restrict__ out) {
    __shared__ __align__(16) u16 Abuf[2][64 * 128];   // 32 KB, [buf][px][ch] swizzled
    __shared__ float w4[576][4];
    __shared__ int y0c[576], x0c[576], y1c[576], x1c[576];

    const int t  = threadIdx.x;
    const int lb = xswiz(blockIdx.x, 64);
    const int b  = lb >> 6;
    const int h  = lb & 63;

    // ---- phase 0: bilinear params for 64 px x 9 taps ----
    for (int i = t; i < 576; i += 256) {
        int p  = i / 9;
        int tt = i - p * 9;
        const float* ob = om + ((size_t)b * OC) * 4096 + (h << 6) + p;
        float dy = ob[(size_t)tt << 12];
        float dx = ob[(size_t)(9 + tt) << 12];
        float m  = ob[(size_t)(18 + tt) << 12];   // sigmoided in K1
        float py = dy + (float)(h - 1 + tt / 3);
        float px = dx + (float)(p - 1 + tt % 3);
        float y0f = floorf(py), x0f = floorf(px);
        float wy = py - y0f, wx = px - x0f;
        int y0 = (int)y0f, x0 = (int)x0f;
        int y1 = y0 + 1,   x1 = x0 + 1;
        float vy0 = ((unsigned)y0 < 64u) ? 1.f : 0.f;
        float vy1 = ((unsigned)y1 < 64u) ? 1.f : 0.f;
        float vx0 = ((unsigned)x0 < 64u) ? 1.f : 0.f;
        float vx1 = ((unsigned)x1 < 64u) ? 1.f : 0.f;
        w4[i][0] = (1.f - wy) * (1.f - wx) * m * vy0 * vx0;
        w4[i][1] = (1.f - wy) * wx         * m * vy0 * vx1;
        w4[i][2] = wy         * (1.f - wx) * m * vy1 * vx0;
        w4[i][3] = wy         * wx         * m * vy1 * vx1;
        y0c[i] = min(max(y0, 0), 63);
        y1c[i] = min(max(y1, 0), 63);
        x0c[i] = min(max(x0, 0), 63);
        x1c[i] = min(max(x1, 0), 63);
    }
    __syncthreads();

    f32x4 acc[4][2];
#pragma unroll
    for (int pt = 0; pt < 4; ++pt)
#pragma unroll
        for (int nt = 0; nt < 2; ++nt) acc[pt][nt] = (f32x4){0.f, 0.f, 0.f, 0.f};

    const int l    = t & 63;
    const int wv   = t >> 6;
    const int row0 = l & 15;
    const int kg   = l >> 4;

    const int sp = t >> 2;          // sampling: pixel 0..63
    const int sc = t & 3;           // sampling: 16B sub-chunk
    const u16* xb = xtb + ((size_t)b << 19);

    uint4 g_[4][4];                 // [k-chunk][corner] gather staging (64 VGPR)

    auto sample_load = [&](int tt) {
        int pi = sp * 9 + tt;
        int o00 = ((y0c[pi] << 6) | x0c[pi]) << 7;
        int o01 = ((y0c[pi] << 6) | x1c[pi]) << 7;
        int o10 = ((y1c[pi] << 6) | x0c[pi]) << 7;
        int o11 = ((y1c[pi] << 6) | x1c[pi]) << 7;
#pragma unroll
        for (int k = 0; k < 4; ++k) {
            int ch = k * 32 + sc * 8;            // 4-lane groups load 64B contiguous
            g_[k][0] = *(const uint4*)(xb + o00 + ch);
            g_[k][1] = *(const uint4*)(xb + o01 + ch);
            g_[k][2] = *(const uint4*)(xb + o10 + ch);
            g_[k][3] = *(const uint4*)(xb + o11 + ch);
        }
    };

    auto sample_finish = [&](int tt, int buf) {
        int pi = sp * 9 + tt;
        float4 W = *(const float4*)(&w4[pi][0]);
        u16* dst = &Abuf[buf][0];
#pragma unroll
        for (int k = 0; k < 4; ++k) {
            uint4 a00 = g_[k][0], a01 = g_[k][1], a10 = g_[k][2], a11 = g_[k][3];
            uint4 ow;
            {
                float e0 = W.x * blo(a00.x) + W.y * blo(a01.x) + W.z * blo(a10.x) + W.w * blo(a11.x);
                float e1 = W.x * bhi(a00.x) + W.y * bhi(a01.x) + W.z * bhi(a10.x) + W.w * bhi(a11.x);
                ow.x = cvtpk(e0, e1);
            }
            {
                float e0 = W.x * blo(a00.y) + W.y * blo(a01.y) + W.z * blo(a10.y) + W.w * blo(a11.y);
                float e1 = W.x * bhi(a00.y) + W.y * bhi(a01.y) + W.z * bhi(a10.y) + W.w * bhi(a11.y);
                ow.y = cvtpk(e0, e1);
            }
            {
                float e0 = W.x * blo(a00.z) + W.y * blo(a01.z) + W.z * blo(a10.z) + W.w * blo(a11.z);
                float e1 = W.x * bhi(a00.z) + W.y * bhi(a01.z) + W.z * bhi(a10.z) + W.w * bhi(a11.z);
                ow.z = cvtpk(e0, e1);
            }
            {
                float e0 = W.x * blo(a00.w) + W.y * blo(a01.w) + W.z * blo(a10.w) + W.w * blo(a11.w);
                float e1 = W.x * bhi(a00.w) + W.y * bhi(a01.w) + W.z * bhi(a10.w) + W.w * bhi(a11.w);
                ow.w = cvtpk(e0, e1);
            }
            int q16 = (k * 4 + sc) ^ (sp & 15);       // full 4-bit XOR: stores ~conflict-free
            *(uint4*)((char*)dst + (sp << 8) + (q16 << 4)) = ow;
        }
    };

    auto domfma = [&](int t9, int buf) {
        const char* Ab = (const char*)&Abuf[buf][0];
#pragma unroll
        for (int s = 0; s < 4; ++s) {
            int q = s * 4 + kg;
            int sw = (q ^ row0) << 4;                 // matches 4-bit store swizzle
            bf16x8 a[4];
#pragma unroll
            for (int pt = 0; pt < 4; ++pt)
                a[pt] = *(const bf16x8*)(Ab + ((pt * 16 + row0) << 8) + sw);
            const u16* B = wbf + ((size_t)t9 << 14) + (s << 12) + (wv << 10) + (l << 3);
            bf16x8 b0 = *(const bf16x8*)(B);
            bf16x8 b1 = *(const bf16x8*)(B + 512);
#pragma unroll
            for (int pt = 0; pt < 4; ++pt) {
                acc[pt][0] = __builtin_amdgcn_mfma_f32_16x16x32_bf16(a[pt], b0, acc[pt][0], 0, 0, 0);
                acc[pt][1] = __builtin_amdgcn_mfma_f32_16x16x32_bf16(a[pt], b1, acc[pt][1], 0, 0, 0);
            }
        }
    };

    sample_load(0);
    sample_finish(0, 0);
    __syncthreads();
    for (int tt = 0; tt < 9; ++tt) {
        if (tt < 8) sample_load(tt + 1);        // issue gathers early
        domfma(tt, tt & 1);                     // MFMA covers gather latency
        if (tt < 8) sample_finish(tt + 1, (tt + 1) & 1);
        __syncthreads();
    }

    // ---- epilogue: acc -> LDS (swizzled f32 [co][px]) -> coalesced global ----
    {
        float* outs = (float*)&Abuf[0][0];    // 128co x 64px f32 = 32 KB
#pragma unroll
        for (int pt = 0; pt < 4; ++pt)
#pragma unroll
            for (int nt = 0; nt < 2; ++nt) {
                int co  = wv * 32 + nt * 16 + row0;
                int pxq = pt * 4 + kg;
                *(f32x4*)((char*)outs + (co << 8) + ((pxq ^ (co & 7)) << 4)) = acc[pt][nt];
            }
    }
    __syncthreads();
    {
        const float* outs = (const float*)&Abuf[0][0];
        int co = t >> 1, ph = t & 1;
        float bb = bias[co];
        float* og = out + (((size_t)(b * COUT + co)) << 12) + (h << 6) + ph * 32;
#pragma unroll
        for (int j = 0; j < 8; ++j) {
            int pxq = ph * 8 + j;
            f32x4 v = *(const f32x4*)((const char*)outs + (co << 8) + ((pxq ^ (co & 7)) << 4));
            float4 r = make_float4(v.x + bb, v.y + bb, v.z + bb, v.w + bb);
            *reinterpret_cast<float4*>(og + j * 4) = r;
        }
    }
}

// ---------------- host ----------------
extern "C" void kernel_launch(void* const* d_in, const int* in_sizes, int n_in,
                              void* d_out, int out_size, void* d_ws, size_t ws_size,
                              hipStream_t stream) {
    const float* x      = (const float*)d_in[0];
    const float* w_off  = (const float*)d_in[1];
    const float* b_off  = (const float*)d_in[2];
    const float* weight = (const float*)d_in[3];
    const float* bias   = (const float*)d_in[4];
    float* out = (float*)d_out;

    float* om  = (float*)d_ws;                        // 884736 f32
    u16*   xtb = (u16*)(om + 884736);                 // 4194304 u16 (NHWC bf16 hi)
    u16*   wbf = xtb + 4194304;                       // 147456 u16 (main B-frags)
    u16*   wop = wbf + 147456;                        // 73728 u16 (offset B-frags hi/lo)
    u16*   xlo = (u16*)d_out;                         // 8 MB scratch inside out (16.7 MB);
                                                      // consumed before k_sample_gemm writes out

    k_pack_w<<<576, 256, 0, stream>>>(weight, wbf);
    k_pack_woff<<<288, 256, 0, stream>>>(w_off, wop);
    k_transpose_x<<<1024, 256, 0, stream>>>(x, xtb, xlo);
    k_off_mfma<<<512, 256, 0, stream>>>(xtb, xlo, wop, b_off, om);
    k_sample_gemm<<<512, 256, 0, stream>>>(xtb, om, wbf, bias, out);
}

// Round 7
// 56.311 us; speedup vs baseline: 1.5017x; 1.3508x over previous
//
#include <hip/hip_runtime.h>
#include <math.h>

#define BATCH 8
#define CIN   128
#define COUT  128
#define HH    64
#define WW    64
#define OC    27        // 3*K2
#define KDIM  1152      // CIN*9

typedef unsigned short u16;
typedef unsigned int   u32;
typedef __attribute__((ext_vector_type(8))) short bf16x8;
typedef __attribute__((ext_vector_type(4))) float f32x4;

__device__ __forceinline__ float b2f(u16 u) {
    return __uint_as_float((u32)u << 16);
}
__device__ __forceinline__ u16 f2b(float f) {   // RTNE
    u32 u = __float_as_uint(f);
    return (u16)((u + 0x7fffu + ((u >> 16) & 1u)) >> 16);
}
__device__ __forceinline__ float blo(u32 u) { return __uint_as_float(u << 16); }
__device__ __forceinline__ float bhi(u32 u) { return __uint_as_float(u & 0xffff0000u); }
__device__ __forceinline__ u32 cvtpk(float lo, float hi) {
    u32 r;
    asm("v_cvt_pk_bf16_f32 %0, %1, %2" : "=v"(r) : "v"(lo), "v"(hi));
    return r;
}

// XCD-ownership swizzle: XCD (o%8) owns image (o%8) end-to-end.
__device__ __forceinline__ int xswiz(int o, int K) { return (o & 7) * K + (o >> 3); }

// ---------------- K_prep: transpose-x + pack_w + pack_woff in one launch ----------
__global__ __launch_bounds__(256) void k_prep(const float* __restrict__ x,
                                              const float* __restrict__ weight,
                                              const float* __restrict__ w_off,
                                              u16* __restrict__ xtb,
                                              u16* __restrict__ xlo,
                                              u16* __restrict__ wbf,
                                              u16* __restrict__ wop) {
    __shared__ float tile[64][65];
    int gbid = blockIdx.x;
    int t = threadIdx.x;
    if (gbid < 1024) {
        // ---- transpose x NCHW f32 -> NHWC bf16 hi/lo ----
        int bid = xswiz(gbid, 128);
        int b   = bid >> 7;
        int c0  = ((bid >> 6) & 1) << 6;
        int hw0 = (bid & 63) << 6;
        int ln  = t & 63;
        int cq  = t >> 6;
#pragma unroll
        for (int r = 0; r < 16; ++r) {
            int c_l = cq * 16 + r;
            tile[c_l][ln] = x[(((size_t)(b * CIN + c0 + c_l)) << 12) + hw0 + ln];
        }
        __syncthreads();
#pragma unroll
        for (int r = 0; r < 16; ++r) {
            int hw_w = cq * 16 + r;
            float v = tile[ln][hw_w];
            u16 hi = f2b(v);
            u16 lo = f2b(v - b2f(hi));
            size_t dst = ((size_t)(b << 12) + hw0 + hw_w) * 128 + c0 + ln;
            xtb[dst] = hi;
            xlo[dst] = lo;
        }
    } else if (gbid < 1600) {
        // ---- pack main weight ----
        int tid = (gbid - 1024) * 256 + t;
        int j  = tid & 7;
        int l  = (tid >> 3) & 63;
        int ni = (tid >> 9) & 7;
        int s  = (tid >> 12) & 3;
        int t9 = tid >> 14;
        int co = ni * 16 + (l & 15);
        int ci = s * 32 + ((l >> 4) << 3) + j;
        wbf[tid] = f2b(weight[co * KDIM + ci * 9 + t9]);
    } else {
        // ---- pack offset weight hi/lo ----
        int tid = (gbid - 1600) * 256 + t;
        int j   = tid & 7;
        int l   = (tid >> 3) & 63;
        int ni  = (tid >> 9) & 1;
        int sg  = (tid >> 10) & 3;
        int rest = tid >> 12;
        int t9  = rest % 9;
        int split = rest / 9;
        int co = ni * 16 + (l & 15);
        int ci = sg * 32 + ((l >> 4) << 3) + j;
        float val = (co < OC) ? w_off[co * KDIM + ci * 9 + t9] : 0.f;
        u16 hi = f2b(val);
        u16 lo = f2b(val - b2f(hi));
        wop[tid] = split ? lo : hi;
    }
}

// ---------------- K1: offset conv via MFMA, 8 waves (px-split x s-split) ----------
__global__ __launch_bounds__(512, 4) void k_off_mfma(const u16* __restrict__ xtb,
                                                     const u16* __restrict__ xlo,
                                                     const u16* __restrict__ wop,
                                                     const float* __restrict__ b_off,
                                                     float* __restrict__ om) {
    __shared__ __align__(16) u16 Xh[3 * 66 * 64];   // 25344 B
    __shared__ __align__(16) u16 Xl[3 * 66 * 64];
    __shared__ __align__(16) float red[4][32][16];  // 8 KB reduce

    const int t    = threadIdx.x;
    const int lb   = xswiz(blockIdx.x, 64);
    const int b    = lb >> 6;
    const int h    = lb & 63;
    const int tl   = t & 255;
    const int sgrp = t >> 8;            // 0/1: ci-quarter split within each half
    const int l    = tl & 63;
    const int wv2  = tl >> 6;           // px group 0..3
    const int row0 = l & 15;
    const int kg   = l >> 4;

    f32x4 acc0 = {0.f, 0.f, 0.f, 0.f};   // co 0..15
    f32x4 acc1 = {0.f, 0.f, 0.f, 0.f};   // co 16..31

    bf16x8 vh_[4], vl_[4];
    const bf16x8 zero8 = {0, 0, 0, 0, 0, 0, 0, 0};

    auto stage_load = [&](int half) {
#pragma unroll
        for (int it = 0; it < 4; ++it) {
            int i = t + it * 512;
            vh_[it] = zero8;
            vl_[it] = zero8;
            if (i < 1584) {
                int row = i / 528;
                int rem = i - row * 528;
                int p = rem >> 3, q = rem & 7;
                int grow = h - 1 + row;
                int gw   = p - 1;
                if ((unsigned)grow < 64u && (unsigned)gw < 64u) {
                    size_t src = ((((size_t)b << 12) + (grow << 6) + gw) << 7) + half * 64 + q * 8;
                    vh_[it] = *(const bf16x8*)(xtb + src);
                    vl_[it] = *(const bf16x8*)(xlo + src);
                }
            }
        }
    };
    auto stage_store = [&]() {
#pragma unroll
        for (int it = 0; it < 4; ++it) {
            int i = t + it * 512;
            if (i < 1584) {
                int row = i / 528;
                int rem = i - row * 528;
                int p = rem >> 3, q = rem & 7;
                int dstb = ((row * 66 + p) << 7) + ((q ^ (p & 7)) << 4);
                *(bf16x8*)((char*)Xh + dstb) = vh_[it];
                *(bf16x8*)((char*)Xl + dstb) = vl_[it];
            }
        }
    };
    auto kloop = [&](int half) {
        for (int tap = 0; tap < 9; ++tap) {
            int kh = tap / 3, kw = tap - kh * 3;
            int p = wv2 * 16 + row0 + kw;          // 0..65
            int rowb = (kh * 66 + p) << 7;
            int q = sgrp * 4 + kg;
            int off = rowb + ((q ^ (p & 7)) << 4);
            bf16x8 ah = *(const bf16x8*)((const char*)Xh + off);
            bf16x8 al = *(const bf16x8*)((const char*)Xl + off);
            int sg = half * 2 + sgrp;
            const u16* B = wop + (((tap * 4 + sg)) << 10) + (l << 3);
            bf16x8 bh0 = *(const bf16x8*)(B);
            bf16x8 bh1 = *(const bf16x8*)(B + 512);
            bf16x8 bl0 = *(const bf16x8*)(B + 36864);
            bf16x8 bl1 = *(const bf16x8*)(B + 36864 + 512);
            acc0 = __builtin_amdgcn_mfma_f32_16x16x32_bf16(ah, bh0, acc0, 0, 0, 0);
            acc1 = __builtin_amdgcn_mfma_f32_16x16x32_bf16(ah, bh1, acc1, 0, 0, 0);
            acc0 = __builtin_amdgcn_mfma_f32_16x16x32_bf16(al, bh0, acc0, 0, 0, 0);
            acc1 = __builtin_amdgcn_mfma_f32_16x16x32_bf16(al, bh1, acc1, 0, 0, 0);
            acc0 = __builtin_amdgcn_mfma_f32_16x16x32_bf16(ah, bl0, acc0, 0, 0, 0);
            acc1 = __builtin_amdgcn_mfma_f32_16x16x32_bf16(ah, bl1, acc1, 0, 0, 0);
        }
    };

    stage_load(0);
    stage_store();
    __syncthreads();
    stage_load(1);           // issue early: latency hides under kloop(0)
    kloop(0);
    __syncthreads();
    stage_store();
    __syncthreads();
    kloop(1);

    // ---- s-group reduction + epilogue ----
    if (sgrp) {
        *(f32x4*)&red[wv2][row0][kg * 4]      = acc0;
        *(f32x4*)&red[wv2][row0 + 16][kg * 4] = acc1;
    }
    __syncthreads();
    if (!sgrp) {
        acc0 += *(const f32x4*)&red[wv2][row0][kg * 4];
        acc1 += *(const f32x4*)&red[wv2][row0 + 16][kg * 4];
        int wpx = wv2 * 16 + (kg << 2);
        int co0 = row0;
        {
            float bb = b_off[co0];
            float4 r = make_float4(acc0.x + bb, acc0.y + bb, acc0.z + bb, acc0.w + bb);
            *(float4*)(om + (((size_t)(b * OC + co0)) << 12) + (h << 6) + wpx) = r;
        }
        int co1 = co0 + 16;
        if (co1 < OC) {
            float bb = b_off[co1];
            float4 r = make_float4(acc1.x + bb, acc1.y + bb, acc1.z + bb, acc1.w + bb);
            if (co1 >= 18) {
                r.x = 1.f / (1.f + expf(-r.x));
                r.y = 1.f / (1.f + expf(-r.y));
                r.z = 1.f / (1.f + expf(-r.z));
                r.w = 1.f / (1.f + expf(-r.w));
            }
            *(float4*)(om + (((size_t)(b * OC + co1)) << 12) + (h << 6) + wpx) = r;
        }
    }
}

// ---------------- K2: bilinear sampling + MFMA GEMM, 8 waves (ci-split) ----------
// block = 64 px x 128 cout; grp 0: ci 0-63, grp 1: ci 64-127. 512 blocks.
__global__ __launch_bounds__(512, 4) void k_sample_gemm(const u16* __restrict__ xtb,
                                                        const float* __restrict__ om,
                                                        const u16* __restrict__ wbf,
                                                        const float* __restrict__ bias,
                                                        float* __restrict__ out) {
    __shared__ __align__(16) u16 Abuf[2][64 * 128];   // 32 KB
    __shared__ float w4[576][4];
    __shared__ int y0c[576], x0c[576], y1c[576], x1c[576];

    const int t  = threadIdx.x;
    const int lb = xswiz(blockIdx.x, 64);
    const int b  = lb >> 6;
    const int h  = lb & 63;

    // ---- phase 0: bilinear params for 64 px x 9 taps ----
    for (int i = t; i < 576; i += 512) {
        int p  = i / 9;
        int tt = i - p * 9;
        const float* ob = om + ((size_t)b * OC) * 4096 + (h << 6) + p;
        float dy = ob[(size_t)tt << 12];
        float dx = ob[(size_t)(9 + tt) << 12];
        float m  = ob[(size_t)(18 + tt) << 12];   // sigmoided in K1
        float py = dy + (float)(h - 1 + tt / 3);
        float px = dx + (float)(p - 1 + tt % 3);
        float y0f = floorf(py), x0f = floorf(px);
        float wy = py - y0f, wx = px - x0f;
        int y0 = (int)y0f, x0 = (int)x0f;
        int y1 = y0 + 1,   x1 = x0 + 1;
        float vy0 = ((unsigned)y0 < 64u) ? 1.f : 0.f;
        float vy1 = ((unsigned)y1 < 64u) ? 1.f : 0.f;
        float vx0 = ((unsigned)x0 < 64u) ? 1.f : 0.f;
        float vx1 = ((unsigned)x1 < 64u) ? 1.f : 0.f;
        w4[i][0] = (1.f - wy) * (1.f - wx) * m * vy0 * vx0;
        w4[i][1] = (1.f - wy) * wx         * m * vy0 * vx1;
        w4[i][2] = wy         * (1.f - wx) * m * vy1 * vx0;
        w4[i][3] = wy         * wx         * m * vy1 * vx1;
        y0c[i] = min(max(y0, 0), 63);
        y1c[i] = min(max(y1, 0), 63);
        x0c[i] = min(max(x0, 0), 63);
        x1c[i] = min(max(x1, 0), 63);
    }
    __syncthreads();

    f32x4 acc[4][2];
#pragma unroll
    for (int pt = 0; pt < 4; ++pt)
#pragma unroll
        for (int nt = 0; nt < 2; ++nt) acc[pt][nt] = (f32x4){0.f, 0.f, 0.f, 0.f};

    const int grp  = t >> 8;        // ci half
    const int tl   = t & 255;
    const int l    = tl & 63;
    const int wv2  = tl >> 6;       // co group (32 each)
    const int row0 = l & 15;
    const int kg   = l >> 4;

    const int sp = tl >> 2;         // sampling: pixel 0..63
    const int sc = tl & 3;          // sampling: 16B sub-chunk within 64B
    const u16* xb = xtb + ((size_t)b << 19);

    uint4 g_[2][4];                 // [k-chunk][corner] (32 VGPR)

    auto sample_load = [&](int tt) {
        int pi = sp * 9 + tt;
        int o00 = (((y0c[pi] << 6) | x0c[pi]) << 7) + grp * 64;
        int o01 = (((y0c[pi] << 6) | x1c[pi]) << 7) + grp * 64;
        int o10 = (((y1c[pi] << 6) | x0c[pi]) << 7) + grp * 64;
        int o11 = (((y1c[pi] << 6) | x1c[pi]) << 7) + grp * 64;
#pragma unroll
        for (int k = 0; k < 2; ++k) {
            int ch = k * 32 + sc * 8;
            g_[k][0] = *(const uint4*)(xb + o00 + ch);
            g_[k][1] = *(const uint4*)(xb + o01 + ch);
            g_[k][2] = *(const uint4*)(xb + o10 + ch);
            g_[k][3] = *(const uint4*)(xb + o11 + ch);
        }
    };

    auto sample_finish = [&](int tt, int buf) {
        int pi = sp * 9 + tt;
        float4 W = *(const float4*)(&w4[pi][0]);
        u16* dst = &Abuf[buf][0];
#pragma unroll
        for (int k = 0; k < 2; ++k) {
            uint4 a00 = g_[k][0], a01 = g_[k][1], a10 = g_[k][2], a11 = g_[k][3];
            uint4 ow;
            {
                float e0 = W.x * blo(a00.x) + W.y * blo(a01.x) + W.z * blo(a10.x) + W.w * blo(a11.x);
                float e1 = W.x * bhi(a00.x) + W.y * bhi(a01.x) + W.z * bhi(a10.x) + W.w * bhi(a11.x);
                ow.x = cvtpk(e0, e1);
            }
            {
                float e0 = W.x * blo(a00.y) + W.y * blo(a01.y) + W.z * blo(a10.y) + W.w * blo(a11.y);
                float e1 = W.x * bhi(a00.y) + W.y * bhi(a01.y) + W.z * bhi(a10.y) + W.w * bhi(a11.y);
                ow.y = cvtpk(e0, e1);
            }
            {
                float e0 = W.x * blo(a00.z) + W.y * blo(a01.z) + W.z * blo(a10.z) + W.w * blo(a11.z);
                float e1 = W.x * bhi(a00.z) + W.y * bhi(a01.z) + W.z * bhi(a10.z) + W.w * bhi(a11.z);
                ow.z = cvtpk(e0, e1);
            }
            {
                float e0 = W.x * blo(a00.w) + W.y * blo(a01.w) + W.z * blo(a10.w) + W.w * blo(a11.w);
                float e1 = W.x * bhi(a00.w) + W.y * bhi(a01.w) + W.z * bhi(a10.w) + W.w * bhi(a11.w);
                ow.w = cvtpk(e0, e1);
            }
            int q16 = (grp * 8 + k * 4 + sc) ^ (sp & 15);
            *(uint4*)((char*)dst + (sp << 8) + (q16 << 4)) = ow;
        }
    };

    auto domfma = [&](int t9, int buf) {
        const char* Ab = (const char*)&Abuf[buf][0];
#pragma unroll
        for (int shalf = 0; shalf < 2; ++shalf) {
            int s = grp * 2 + shalf;
            int q = s * 4 + kg;
            int sw = (q ^ row0) << 4;
            bf16x8 a[4];
#pragma unroll
            for (int pt = 0; pt < 4; ++pt)
                a[pt] = *(const bf16x8*)(Ab + ((pt * 16 + row0) << 8) + sw);
            const u16* B = wbf + ((size_t)t9 << 14) + (s << 12) + (wv2 << 10) + (l << 3);
            bf16x8 b0 = *(const bf16x8*)(B);
            bf16x8 b1 = *(const bf16x8*)(B + 512);
#pragma unroll
            for (int pt = 0; pt < 4; ++pt) {
                acc[pt][0] = __builtin_amdgcn_mfma_f32_16x16x32_bf16(a[pt], b0, acc[pt][0], 0, 0, 0);
                acc[pt][1] = __builtin_amdgcn_mfma_f32_16x16x32_bf16(a[pt], b1, acc[pt][1], 0, 0, 0);
            }
        }
    };

    sample_load(0);
    sample_finish(0, 0);
    __syncthreads();
    for (int tt = 0; tt < 9; ++tt) {
        if (tt < 8) sample_load(tt + 1);        // issue gathers early
        domfma(tt, tt & 1);                     // MFMA covers gather latency
        if (tt < 8) sample_finish(tt + 1, (tt + 1) & 1);
        __syncthreads();
    }

    // ---- ci-group reduce + epilogue via LDS ----
    float* outs = (float*)&Abuf[0][0];          // 128co x 64px f32 = 32 KB
    if (grp) {
#pragma unroll
        for (int pt = 0; pt < 4; ++pt)
#pragma unroll
            for (int nt = 0; nt < 2; ++nt) {
                int co  = wv2 * 32 + nt * 16 + row0;
                int pxq = pt * 4 + kg;
                *(f32x4*)((char*)outs + (co << 8) + ((pxq ^ (co & 7)) << 4)) = acc[pt][nt];
            }
    }
    __syncthreads();
    if (!grp) {
#pragma unroll
        for (int pt = 0; pt < 4; ++pt)
#pragma unroll
            for (int nt = 0; nt < 2; ++nt) {
                int co  = wv2 * 32 + nt * 16 + row0;
                int pxq = pt * 4 + kg;
                char* ad = (char*)outs + (co << 8) + ((pxq ^ (co & 7)) << 4);
                f32x4 v = *(const f32x4*)ad;
                *(f32x4*)ad = v + acc[pt][nt];
            }
    }
    __syncthreads();
    {
        int co = t >> 2, qt = t & 3;
        float bb = bias[co];
        float* og = out + (((size_t)(b * COUT + co)) << 12) + (h << 6);
#pragma unroll
        for (int j = 0; j < 4; ++j) {
            int pxq = qt * 4 + j;
            f32x4 v = *(const f32x4*)((const char*)outs + (co << 8) + ((pxq ^ (co & 7)) << 4));
            float4 r = make_float4(v.x + bb, v.y + bb, v.z + bb, v.w + bb);
            *reinterpret_cast<float4*>(og + pxq * 4) = r;
        }
    }
}

// ---------------- host ----------------
extern "C" void kernel_launch(void* const* d_in, const int* in_sizes, int n_in,
                              void* d_out, int out_size, void* d_ws, size_t ws_size,
                              hipStream_t stream) {
    const float* x      = (const float*)d_in[0];
    const float* w_off  = (const float*)d_in[1];
    const float* b_off  = (const float*)d_in[2];
    const float* weight = (const float*)d_in[3];
    const float* bias   = (const float*)d_in[4];
    float* out = (float*)d_out;

    float* om  = (float*)d_ws;                        // 884736 f32
    u16*   xtb = (u16*)(om + 884736);                 // 4194304 u16 (NHWC bf16 hi)
    u16*   wbf = xtb + 4194304;                       // 147456 u16 (main B-frags)
    u16*   wop = wbf + 147456;                        // 73728 u16 (offset B-frags hi/lo)
    u16*   xlo = (u16*)d_out;                         // 8 MB scratch inside out;
                                                      // consumed before k_sample_gemm writes out

    k_prep<<<1888, 256, 0, stream>>>(x, weight, w_off, xtb, xlo, wbf, wop);
    k_off_mfma<<<512, 512, 0, stream>>>(xtb, xlo, wop, b_off, om);
    k_sample_gemm<<<512, 512, 0, stream>>>(xtb, om, wbf, bias, out);
}

// Round 8
// 48.350 us; speedup vs baseline: 1.7489x; 1.1647x over previous
//
#include <hip/hip_runtime.h>
#include <math.h>

#define BATCH 8
#define CIN   128
#define COUT  128
#define HH    64
#define WW    64
#define OC    27        // 3*K2
#define KDIM  1152      // CIN*9

typedef unsigned short u16;
typedef unsigned int   u32;
typedef __attribute__((ext_vector_type(8))) short bf16x8;
typedef __attribute__((ext_vector_type(4))) float f32x4;

__device__ __forceinline__ float b2f(u16 u) {
    return __uint_as_float((u32)u << 16);
}
__device__ __forceinline__ u16 f2b(float f) {   // RTNE
    u32 u = __float_as_uint(f);
    return (u16)((u + 0x7fffu + ((u >> 16) & 1u)) >> 16);
}
__device__ __forceinline__ float blo(u32 u) { return __uint_as_float(u << 16); }
__device__ __forceinline__ float bhi(u32 u) { return __uint_as_float(u & 0xffff0000u); }
__device__ __forceinline__ u32 cvtpk(float lo, float hi) {
    u32 r;
    asm("v_cvt_pk_bf16_f32 %0, %1, %2" : "=v"(r) : "v"(lo), "v"(hi));
    return r;
}
__device__ __forceinline__ bf16x8 pack8(u32 a, u32 b, u32 c, u32 d) {
    union { u32 u[4]; bf16x8 v; } z;
    z.u[0] = a; z.u[1] = b; z.u[2] = c; z.u[3] = d;
    return z.v;
}

// XCD-ownership swizzle: XCD (o%8) owns image (o%8) end-to-end.
__device__ __forceinline__ int xswiz(int o, int K) { return (o & 7) * K + (o >> 3); }

// ---------------- K_prep: transpose-x(hi only) + pack_w + pack_woff ----------
__global__ __launch_bounds__(256) void k_prep(const float* __restrict__ x,
                                              const float* __restrict__ weight,
                                              const float* __restrict__ w_off,
                                              u16* __restrict__ xtb,
                                              u16* __restrict__ wbf,
                                              u16* __restrict__ wop) {
    __shared__ float tile[64][65];
    int gbid = blockIdx.x;
    int t = threadIdx.x;
    if (gbid < 1024) {
        // ---- transpose x NCHW f32 -> NHWC bf16 (hi only) ----
        int bid = xswiz(gbid, 128);
        int b   = bid >> 7;
        int c0  = ((bid >> 6) & 1) << 6;
        int hw0 = (bid & 63) << 6;
        int ln  = t & 63;
        int cq  = t >> 6;
#pragma unroll
        for (int r = 0; r < 16; ++r) {
            int c_l = cq * 16 + r;
            tile[c_l][ln] = x[(((size_t)(b * CIN + c0 + c_l)) << 12) + hw0 + ln];
        }
        __syncthreads();
#pragma unroll
        for (int r = 0; r < 16; ++r) {
            int hw_w = cq * 16 + r;
            xtb[((size_t)(b << 12) + hw0 + hw_w) * 128 + c0 + ln] = f2b(tile[ln][hw_w]);
        }
    } else if (gbid < 1600) {
        // ---- pack main weight (B-frag layout: n=co from l&15, k=ci) ----
        int tid = (gbid - 1024) * 256 + t;
        int j  = tid & 7;
        int l  = (tid >> 3) & 63;
        int ni = (tid >> 9) & 7;
        int s  = (tid >> 12) & 3;
        int t9 = tid >> 14;
        int co = ni * 16 + (l & 15);
        int ci = s * 32 + ((l >> 4) << 3) + j;
        wbf[tid] = f2b(weight[co * KDIM + ci * 9 + t9]);
    } else {
        // ---- pack offset weight hi/lo (A-frag layout: m=co from l&15, k=ci) ----
        int tid = (gbid - 1600) * 256 + t;
        int j   = tid & 7;
        int l   = (tid >> 3) & 63;
        int ni  = (tid >> 9) & 1;
        int sg  = (tid >> 10) & 3;
        int rest = tid >> 12;
        int t9  = rest % 9;
        int split = rest / 9;
        int co = ni * 16 + (l & 15);
        int ci = sg * 32 + ((l >> 4) << 3) + j;
        float val = (co < OC) ? w_off[co * KDIM + ci * 9 + t9] : 0.f;
        u16 hi = f2b(val);
        u16 lo = f2b(val - b2f(hi));
        wop[tid] = split ? lo : hi;
    }
}

// ---------------- K_fused: offset-conv MFMA (phase A) + sample+GEMM (phase B) ----
// 512 blocks (b,h) x 512 threads. Phase A: A=w_off frags, B=x frags from NCHW f32.
#define CST 228   // f32 stride per ci in Xf (3*68 rows + bank pad headroom)
__global__ __launch_bounds__(512, 4) void k_fused(const float* __restrict__ x,
                                                  const u16* __restrict__ xtb,
                                                  const u16* __restrict__ wop,
                                                  const u16* __restrict__ wbf,
                                                  const float* __restrict__ b_off,
                                                  const float* __restrict__ bias,
                                                  float* __restrict__ out) {
    __shared__ __align__(16) char smem[73472];
    float* Xf  = (float*)smem;                 // phase A: [64 ci][CST] f32 = 58368 B
    float* red = (float*)(smem + 58368);       // phase A: 4x64x8 f32 = 8192 B
    float* omf = (float*)(smem + 66560);       // om row [27 co][64 px] f32 = 6912 B

    const int t  = threadIdx.x;
    const int lb = xswiz(blockIdx.x, 64);
    const int b  = lb >> 6;
    const int h  = lb & 63;
    const int l    = t & 63;
    const int wv   = t >> 6;
    const int l15  = l & 15;
    const int lg   = l >> 4;

    // ================= PHASE A: offset conv =================
    {
        const int ntile = wv & 3;       // px tile (16 px)
        const int kgrp  = wv >> 2;      // ci 32-chunk within staged half

        // zero the px=64..67 pad slots (edge gw=-1 / gw=64 read targets)
        if (t < 192) {
            int ci = t & 63, row = t >> 6;
            int idx = ci * CST + row * 68 + (((ci >> 3) & 3) << 3) + 64;
            *(float4*)(Xf + idx) = make_float4(0.f, 0.f, 0.f, 0.f);
        }

        f32x4 acc0 = {0.f, 0.f, 0.f, 0.f};   // co 0..15
        f32x4 acc1 = {0.f, 0.f, 0.f, 0.f};   // co 16..31
        float4 st_[6];

        auto stageA_load = [&](int half) {
#pragma unroll
            for (int it = 0; it < 6; ++it) {
                int slot = t + it * 512;          // 3072 slots = 192 pairs x 16
                int pair = slot >> 4, ln16 = slot & 15;
                int row = pair >> 6, ci = pair & 63;
                int grow = h - 1 + row;
                float4 v = make_float4(0.f, 0.f, 0.f, 0.f);
                if ((unsigned)grow < 64u)
                    v = *(const float4*)(x + (((size_t)(b * CIN + half * 64 + ci)) << 12)
                                           + (grow << 6) + ln16 * 4);
                st_[it] = v;
            }
        };
        auto stageA_store = [&]() {
#pragma unroll
            for (int it = 0; it < 6; ++it) {
                int slot = t + it * 512;
                int pair = slot >> 4, ln16 = slot & 15;
                int row = pair >> 6, ci = pair & 63;
                int idx = ci * CST + row * 68 + (((ci >> 3) & 3) << 3) + ln16 * 4;
                *(float4*)(Xf + idx) = st_[it];
            }
        };
        auto kloopA = [&](int half) {
            for (int tap = 0; tap < 9; ++tap) {
                int kh = tap / 3, kw = tap - kh * 3;
                int gw = ntile * 16 + kw - 1 + l15;
                int px = (gw < 0) ? 64 : ((gw > 63) ? 65 : gw);
                int ci0 = kgrp * 32 + (lg << 3);
                int base = ci0 * CST + kh * 68 + (((ci0 >> 3) & 3) << 3) + px;
                float f0 = Xf[base], f1 = Xf[base + CST];
                float f2 = Xf[base + 2 * CST], f3 = Xf[base + 3 * CST];
                float f4 = Xf[base + 4 * CST], f5 = Xf[base + 5 * CST];
                float f6 = Xf[base + 6 * CST], f7 = Xf[base + 7 * CST];
                u32 h0 = cvtpk(f0, f1), h1 = cvtpk(f2, f3);
                u32 h2 = cvtpk(f4, f5), h3 = cvtpk(f6, f7);
                u32 l0 = cvtpk(f0 - blo(h0), f1 - bhi(h0));
                u32 l1 = cvtpk(f2 - blo(h1), f3 - bhi(h1));
                u32 l2 = cvtpk(f4 - blo(h2), f5 - bhi(h2));
                u32 l3 = cvtpk(f6 - blo(h3), f7 - bhi(h3));
                bf16x8 ah = pack8(h0, h1, h2, h3);
                bf16x8 al = pack8(l0, l1, l2, l3);
                int sg = half * 2 + kgrp;
                const u16* B = wop + (((tap * 4 + sg) * 2) << 9) + (l << 3);
                bf16x8 wh0 = *(const bf16x8*)(B);
                bf16x8 wh1 = *(const bf16x8*)(B + 512);
                bf16x8 wl0 = *(const bf16x8*)(B + 36864);
                bf16x8 wl1 = *(const bf16x8*)(B + 36864 + 512);
                acc0 = __builtin_amdgcn_mfma_f32_16x16x32_bf16(wh0, ah, acc0, 0, 0, 0);
                acc1 = __builtin_amdgcn_mfma_f32_16x16x32_bf16(wh1, ah, acc1, 0, 0, 0);
                acc0 = __builtin_amdgcn_mfma_f32_16x16x32_bf16(wl0, ah, acc0, 0, 0, 0);
                acc1 = __builtin_amdgcn_mfma_f32_16x16x32_bf16(wl1, ah, acc1, 0, 0, 0);
                acc0 = __builtin_amdgcn_mfma_f32_16x16x32_bf16(wh0, al, acc0, 0, 0, 0);
                acc1 = __builtin_amdgcn_mfma_f32_16x16x32_bf16(wh1, al, acc1, 0, 0, 0);
            }
        };

        stageA_load(0);
        stageA_store();
        __syncthreads();
        stageA_load(1);          // issue half-1 HBM/L2 loads early (T14)
        kloopA(0);
        __syncthreads();
        stageA_store();
        __syncthreads();
        kloopA(1);

        // reduce over kgrp, then bias/sigmoid -> om row in LDS
        if (kgrp) {
            float* rp = red + (((ntile << 6) + l) << 3);
            *(f32x4*)rp = acc0;
            *(f32x4*)(rp + 4) = acc1;
        }
        __syncthreads();
        if (!kgrp) {
            const float* rp = red + (((ntile << 6) + l) << 3);
            acc0 += *(const f32x4*)rp;
            acc1 += *(const f32x4*)(rp + 4);
            int px = ntile * 16 + l15;
            int co0 = lg << 2;
#pragma unroll
            for (int r = 0; r < 4; ++r)
                omf[((co0 + r) << 6) + px] = acc0[r] + b_off[co0 + r];
            int co1 = 16 + (lg << 2);
#pragma unroll
            for (int r = 0; r < 4; ++r) {
                int co = co1 + r;
                if (co < OC) {
                    float v = acc1[r] + b_off[co];
                    if (co >= 18) v = 1.f / (1.f + expf(-v));
                    omf[(co << 6) + px] = v;
                }
            }
        }
        __syncthreads();
    }

    // ================= PHASE B: bilinear sampling + MFMA GEMM =================
    float (*w4)[4] = (float (*)[4])(smem + 32768);   // 9216 B
    int* y0c = (int*)(smem + 41984);
    int* x0c = (int*)(smem + 44288);
    int* y1c = (int*)(smem + 46592);
    int* x1c = (int*)(smem + 48896);                 // end 51200 (under Xf/red region)

    // ---- bilinear params for 64 px x 9 taps (om from LDS) ----
    for (int i = t; i < 576; i += 512) {
        int p  = i / 9;
        int tt = i - p * 9;
        float dy = omf[(tt << 6) + p];
        float dx = omf[((9 + tt) << 6) + p];
        float m  = omf[((18 + tt) << 6) + p];   // sigmoided in phase A
        float py = dy + (float)(h - 1 + tt / 3);
        float px = dx + (float)(p - 1 + tt % 3);
        float y0f = floorf(py), x0f = floorf(px);
        float wy = py - y0f, wx = px - x0f;
        int y0 = (int)y0f, x0 = (int)x0f;
        int y1 = y0 + 1,   x1 = x0 + 1;
        float vy0 = ((unsigned)y0 < 64u) ? 1.f : 0.f;
        float vy1 = ((unsigned)y1 < 64u) ? 1.f : 0.f;
        float vx0 = ((unsigned)x0 < 64u) ? 1.f : 0.f;
        float vx1 = ((unsigned)x1 < 64u) ? 1.f : 0.f;
        w4[i][0] = (1.f - wy) * (1.f - wx) * m * vy0 * vx0;
        w4[i][1] = (1.f - wy) * wx         * m * vy0 * vx1;
        w4[i][2] = wy         * (1.f - wx) * m * vy1 * vx0;
        w4[i][3] = wy         * wx         * m * vy1 * vx1;
        y0c[i] = min(max(y0, 0), 63);
        y1c[i] = min(max(y1, 0), 63);
        x0c[i] = min(max(x0, 0), 63);
        x1c[i] = min(max(x1, 0), 63);
    }
    __syncthreads();

    f32x4 acc[4][2];
#pragma unroll
    for (int pt = 0; pt < 4; ++pt)
#pragma unroll
        for (int nt = 0; nt < 2; ++nt) acc[pt][nt] = (f32x4){0.f, 0.f, 0.f, 0.f};

    const int grp  = t >> 8;        // ci half
    const int tl   = t & 255;
    const int l2   = tl & 63;
    const int wv2  = tl >> 6;       // co group (32 each)
    const int row0 = l2 & 15;
    const int kg   = l2 >> 4;

    const int sp = tl >> 2;         // sampling: pixel 0..63
    const int sc = tl & 3;          // sampling: 16B sub-chunk within 64B
    const u16* xb = xtb + ((size_t)b << 19);

    uint4 g_[2][4];

    auto sample_load = [&](int tt) {
        int pi = sp * 9 + tt;
        int o00 = (((y0c[pi] << 6) | x0c[pi]) << 7) + grp * 64;
        int o01 = (((y0c[pi] << 6) | x1c[pi]) << 7) + grp * 64;
        int o10 = (((y1c[pi] << 6) | x0c[pi]) << 7) + grp * 64;
        int o11 = (((y1c[pi] << 6) | x1c[pi]) << 7) + grp * 64;
#pragma unroll
        for (int k = 0; k < 2; ++k) {
            int ch = k * 32 + sc * 8;
            g_[k][0] = *(const uint4*)(xb + o00 + ch);
            g_[k][1] = *(const uint4*)(xb + o01 + ch);
            g_[k][2] = *(const uint4*)(xb + o10 + ch);
            g_[k][3] = *(const uint4*)(xb + o11 + ch);
        }
    };

    auto sample_finish = [&](int tt, int buf) {
        int pi = sp * 9 + tt;
        float4 W = *(const float4*)(&w4[pi][0]);
        u16* dst = (u16*)(smem + buf * 16384);
#pragma unroll
        for (int k = 0; k < 2; ++k) {
            uint4 a00 = g_[k][0], a01 = g_[k][1], a10 = g_[k][2], a11 = g_[k][3];
            uint4 ow;
            {
                float e0 = W.x * blo(a00.x) + W.y * blo(a01.x) + W.z * blo(a10.x) + W.w * blo(a11.x);
                float e1 = W.x * bhi(a00.x) + W.y * bhi(a01.x) + W.z * bhi(a10.x) + W.w * bhi(a11.x);
                ow.x = cvtpk(e0, e1);
            }
            {
                float e0 = W.x * blo(a00.y) + W.y * blo(a01.y) + W.z * blo(a10.y) + W.w * blo(a11.y);
                float e1 = W.x * bhi(a00.y) + W.y * bhi(a01.y) + W.z * bhi(a10.y) + W.w * bhi(a11.y);
                ow.y = cvtpk(e0, e1);
            }
            {
                float e0 = W.x * blo(a00.z) + W.y * blo(a01.z) + W.z * blo(a10.z) + W.w * blo(a11.z);
                float e1 = W.x * bhi(a00.z) + W.y * bhi(a01.z) + W.z * bhi(a10.z) + W.w * bhi(a11.z);
                ow.z = cvtpk(e0, e1);
            }
            {
                float e0 = W.x * blo(a00.w) + W.y * blo(a01.w) + W.z * blo(a10.w) + W.w * blo(a11.w);
                float e1 = W.x * bhi(a00.w) + W.y * bhi(a01.w) + W.z * bhi(a10.w) + W.w * bhi(a11.w);
                ow.w = cvtpk(e0, e1);
            }
            int q16 = (grp * 8 + k * 4 + sc) ^ (sp & 15);
            *(uint4*)((char*)dst + (sp << 8) + (q16 << 4)) = ow;
        }
    };

    auto domfma = [&](int t9, int buf) {
        const char* Ab = (const char*)(smem + buf * 16384);
#pragma unroll
        for (int shalf = 0; shalf < 2; ++shalf) {
            int s = grp * 2 + shalf;
            int q = s * 4 + kg;
            int sw = (q ^ row0) << 4;
            bf16x8 a[4];
#pragma unroll
            for (int pt = 0; pt < 4; ++pt)
                a[pt] = *(const bf16x8*)(Ab + ((pt * 16 + row0) << 8) + sw);
            const u16* B = wbf + ((size_t)t9 << 14) + (s << 12) + (wv2 << 10) + (l2 << 3);
            bf16x8 b0 = *(const bf16x8*)(B);
            bf16x8 b1 = *(const bf16x8*)(B + 512);
#pragma unroll
            for (int pt = 0; pt < 4; ++pt) {
                acc[pt][0] = __builtin_amdgcn_mfma_f32_16x16x32_bf16(a[pt], b0, acc[pt][0], 0, 0, 0);
                acc[pt][1] = __builtin_amdgcn_mfma_f32_16x16x32_bf16(a[pt], b1, acc[pt][1], 0, 0, 0);
            }
        }
    };

    sample_load(0);
    sample_finish(0, 0);
    __syncthreads();
    for (int tt = 0; tt < 9; ++tt) {
        if (tt < 8) sample_load(tt + 1);        // issue gathers early
        domfma(tt, tt & 1);                     // MFMA covers gather latency
        if (tt < 8) sample_finish(tt + 1, (tt + 1) & 1);
        __syncthreads();
    }

    // ---- ci-group reduce + epilogue via LDS ----
    float* outs = (float*)smem;                 // 128co x 64px f32 = 32 KB
    if (grp) {
#pragma unroll
        for (int pt = 0; pt < 4; ++pt)
#pragma unroll
            for (int nt = 0; nt < 2; ++nt) {
                int co  = wv2 * 32 + nt * 16 + row0;
                int pxq = pt * 4 + kg;
                *(f32x4*)((char*)outs + (co << 8) + ((pxq ^ (co & 7)) << 4)) = acc[pt][nt];
            }
    }
    __syncthreads();
    if (!grp) {
#pragma unroll
        for (int pt = 0; pt < 4; ++pt)
#pragma unroll
            for (int nt = 0; nt < 2; ++nt) {
                int co  = wv2 * 32 + nt * 16 + row0;
                int pxq = pt * 4 + kg;
                char* ad = (char*)outs + (co << 8) + ((pxq ^ (co & 7)) << 4);
                f32x4 v = *(const f32x4*)ad;
                *(f32x4*)ad = v + acc[pt][nt];
            }
    }
    __syncthreads();
    {
        int co = t >> 2, qt = t & 3;
        float bb = bias[co];
        float* og = out + (((size_t)(b * COUT + co)) << 12) + (h << 6);
#pragma unroll
        for (int j = 0; j < 4; ++j) {
            int pxq = qt * 4 + j;
            f32x4 v = *(const f32x4*)((const char*)outs + (co << 8) + ((pxq ^ (co & 7)) << 4));
            float4 r = make_float4(v.x + bb, v.y + bb, v.z + bb, v.w + bb);
            *reinterpret_cast<float4*>(og + pxq * 4) = r;
        }
    }
}

// ---------------- host ----------------
extern "C" void kernel_launch(void* const* d_in, const int* in_sizes, int n_in,
                              void* d_out, int out_size, void* d_ws, size_t ws_size,
                              hipStream_t stream) {
    const float* x      = (const float*)d_in[0];
    const float* w_off  = (const float*)d_in[1];
    const float* b_off  = (const float*)d_in[2];
    const float* weight = (const float*)d_in[3];
    const float* bias   = (const float*)d_in[4];
    float* out = (float*)d_out;

    u16* xtb = (u16*)d_ws;            // 4194304 u16 (NHWC bf16 hi)
    u16* wbf = xtb + 4194304;         // 147456 u16 (main GEMM B-frags)
    u16* wop = wbf + 147456;          // 73728 u16 (offset A-frags hi/lo)
                                      // total ws use ~8.8 MB

    k_prep<<<1888, 256, 0, stream>>>(x, weight, w_off, xtb, wbf, wop);
    k_fused<<<512, 512, 0, stream>>>(x, xtb, wop, wbf, b_off, bias, out);
}